// Round 10
// baseline (72.829 us; speedup 1.0000x reference)
//
#include <hip/hip_runtime.h>
#include <hip/hip_bf16.h>

// Problem constants
#define TT 2048
#define BB 4
#define CC 512
#define HH 16
#define KK 31
#define PP 15
#define MM (TT*BB)      // 8192 rows
#define NPAD 512        // HK=496 padded to 512 (pad rows of Wl are zero)

typedef __bf16 bf16x8 __attribute__((ext_vector_type(8)));
typedef float f32x4 __attribute__((ext_vector_type(4)));
typedef unsigned short ushort8 __attribute__((ext_vector_type(8)));
typedef unsigned short ushort4v __attribute__((ext_vector_type(4)));

__device__ __forceinline__ float bf2f(unsigned short u) {
    return __uint_as_float(((unsigned int)u) << 16);
}
__device__ __forceinline__ unsigned short f2bf(float f) {
    unsigned int x = __float_as_uint(f);
    x += 0x7fffu + ((x >> 16) & 1u);
    return (unsigned short)(x >> 16);
}

// ---------------------------------------------------------------------------
// cast fp32 -> bf16 for x (4 elems/thread)
// ---------------------------------------------------------------------------
__global__ __launch_bounds__(256) void cast_x(const float* __restrict__ src,
                                              unsigned short* __restrict__ dst) {
    const int i = (blockIdx.x * 256 + threadIdx.x) * 4;
    const float4 v = *(const float4*)&src[i];
    ushort4v o = { f2bf(v.x), f2bf(v.y), f2bf(v.z), f2bf(v.w) };
    *(ushort4v*)&dst[i] = o;
}

// ---------------------------------------------------------------------------
// cast weights: W1 -> Wcomb[0:512] (row-major bf16), Wl -> Wlb (zero-padded
// to 512 rows), W2 -> W2b.
// ---------------------------------------------------------------------------
__global__ __launch_bounds__(256) void cast_weights(const float* __restrict__ W1,
                                                    const float* __restrict__ Wl,
                                                    const float* __restrict__ W2,
                                                    unsigned short* __restrict__ W1b,
                                                    unsigned short* __restrict__ Wlb,
                                                    unsigned short* __restrict__ W2b) {
    const int b = blockIdx.x;
    const int i = (b & 255) * 1024 + threadIdx.x * 4;
    const float* src;
    unsigned short* dst;
    int n_src = 262144;
    if (b < 256)      { src = W1; dst = W1b; }
    else if (b < 512) { src = Wl; dst = Wlb; n_src = HH * KK * CC; }
    else              { src = W2; dst = W2b; }
    ushort4v o = {0, 0, 0, 0};
    if (i < n_src) {
        const float4 v = *(const float4*)&src[i];
        o[0] = f2bf(v.x); o[1] = f2bf(v.y); o[2] = f2bf(v.z); o[3] = f2bf(v.w);
    }
    *(ushort4v*)&dst[i] = o;
}

// ---------------------------------------------------------------------------
// transpose-cast: W1t[c][d] = bf16(W1[d][c]).  64x64 LDS tiles, grid (8,8).
// ---------------------------------------------------------------------------
__global__ __launch_bounds__(256) void transpose_W1(const float* __restrict__ W1,
                                                    unsigned short* __restrict__ W1t) {
    __shared__ float t[64][65];
    const int r16 = threadIdx.x >> 4;        // 0..15
    const int c4  = (threadIdx.x & 15) * 4;  // 0..60
    const int bd = blockIdx.y * 64, bc = blockIdx.x * 64;
    #pragma unroll
    for (int i = 0; i < 4; ++i) {
        const int row = i * 16 + r16;
        const float4 v = *(const float4*)&W1[(size_t)(bd + row) * 512 + bc + c4];
        t[row][c4 + 0] = v.x; t[row][c4 + 1] = v.y;
        t[row][c4 + 2] = v.z; t[row][c4 + 3] = v.w;
    }
    __syncthreads();
    #pragma unroll
    for (int i = 0; i < 4; ++i) {
        const int orow = i * 16 + r16;       // c-index within tile
        ushort4v o;
        #pragma unroll
        for (int j = 0; j < 4; ++j) o[j] = f2bf(t[c4 + j][orow]);
        *(ushort4v*)&W1t[(size_t)(bc + orow) * 512 + bd + c4] = o;
    }
}

// ---------------------------------------------------------------------------
// bias_comb[0:512] = b1; bias_comb[512+e] = sum_d Wl[e][d]*b1[d] (0 for pad).
// grid 8 x 256 thr; 4 lanes per row, shfl reduce.
// ---------------------------------------------------------------------------
__global__ __launch_bounds__(256) void make_bias(const float* __restrict__ b1,
                                                 const float* __restrict__ Wl,
                                                 float* __restrict__ bias_comb) {
    const int bid = blockIdx.x, tid = threadIdx.x;
    if (tid < 64) bias_comb[bid * 64 + tid] = b1[bid * 64 + tid];
    const int r = bid * 64 + (tid >> 2);
    const int q = tid & 3;
    float sm = 0.f;
    if (r < HH * KK) {
        #pragma unroll
        for (int j = 0; j < 32; ++j) {
            const float4 wv = *(const float4*)&Wl[(size_t)r * 512 + q * 128 + j * 4];
            const float4 bv = *(const float4*)&b1[q * 128 + j * 4];
            sm += wv.x * bv.x + wv.y * bv.y + wv.z * bv.z + wv.w * bv.w;
        }
    }
    sm += __shfl_xor(sm, 1, 4);
    sm += __shfl_xor(sm, 2, 4);
    if (q == 0) bias_comb[512 + r] = sm;
}

// ---------------------------------------------------------------------------
// bf16 MFMA GEMM-NT, 3-stage counted-vmcnt pipeline (R7 structure).
// C[m,n] = sum_k A[m,k]*B[n,k] (+bias[n]); K fixed 512 (NT=8 x BK=64).
// 128x64 tile, 256 thr = 4 waves (2x2), each wave 64x32 out.
// MODE 0: f32 out (stride N). MODE 1: bf16 out (stride N).
// MODE 2: split bf16 out — col<512 -> Cout (stride 512), else Cout2 (stride
// 512, col-512). bias indexed by full col.
// LDS 72 KB -> 2 blocks/CU. Swizzle slot^=(row&7), both sides.
// ---------------------------------------------------------------------------
#define GBM 128
#define GBN 64
#define GBK 64
#define KC  512
#define NT  8

#define STAGE(kt, buf)                                                                         \
    do {                                                                                       \
        const int k0_ = (kt) * GBK;                                                            \
        _Pragma("unroll")                                                                      \
        for (int j = 0; j < 4; ++j)                                                            \
            __builtin_amdgcn_global_load_lds(                                                  \
                (const __attribute__((address_space(1))) void*)(gA[j] + k0_),                  \
                (__attribute__((address_space(3))) void*)(&As[buf][0] + j * 2048 + wv * 512),  \
                16, 0, 0);                                                                     \
        _Pragma("unroll")                                                                      \
        for (int j = 0; j < 2; ++j)                                                            \
            __builtin_amdgcn_global_load_lds(                                                  \
                (const __attribute__((address_space(1))) void*)(gB[j] + k0_),                  \
                (__attribute__((address_space(3))) void*)(&Bs[buf][0] + j * 2048 + wv * 512),  \
                16, 0, 0);                                                                     \
    } while (0)

template<int MODE>
__global__ __launch_bounds__(256, 2) void gemm_nt_mfma(const unsigned short* __restrict__ A,
                                                       const unsigned short* __restrict__ B,
                                                       const float* __restrict__ bias,
                                                       void* __restrict__ Cout,
                                                       void* __restrict__ Cout2,
                                                       int N, int nn) {
    __shared__ short As[3][GBM * GBK];   // 3 x 16 KB
    __shared__ short Bs[3][GBN * GBK];   // 3 x 8 KB

    const int tid = threadIdx.x;
    const int l   = tid & 63;
    const int wv  = tid >> 6;      // wave 0..3
    const int wr  = wv >> 1;
    const int wc  = wv & 1;

    // chunked XCD swizzle (gridDim.x % 8 == 0)
    const int s  = (blockIdx.x & 7) * (gridDim.x >> 3) + (blockIdx.x >> 3);
    const int bm = (s / nn) * GBM;
    const int bn = (s % nn) * GBN;

    const unsigned short* gA[4];
    const unsigned short* gB[2];
    #pragma unroll
    for (int j = 0; j < 4; ++j) {
        const int idx16 = j * 256 + tid;
        const int r  = idx16 >> 3;
        const int sl = (idx16 & 7) ^ (r & 7);
        gA[j] = A + (size_t)(bm + r) * KC + sl * 8;
    }
    #pragma unroll
    for (int j = 0; j < 2; ++j) {
        const int idx16 = j * 256 + tid;
        const int r  = idx16 >> 3;
        const int sl = (idx16 & 7) ^ (r & 7);
        gB[j] = B + (size_t)(bn + r) * KC + sl * 8;
    }

    f32x4 acc[4][2] = {};

    const int lr = l & 15;
    const int ls = l >> 4;
    int offA[4][2], offB[2][2];
    #pragma unroll
    for (int mi = 0; mi < 4; ++mi) {
        const int r = wr * 64 + mi * 16 + lr;
        #pragma unroll
        for (int ks = 0; ks < 2; ++ks)
            offA[mi][ks] = r * 64 + (((ks * 4 + ls) ^ (r & 7)) * 8);
    }
    #pragma unroll
    for (int ni = 0; ni < 2; ++ni) {
        const int r = wc * 32 + ni * 16 + lr;
        #pragma unroll
        for (int ks = 0; ks < 2; ++ks)
            offB[ni][ks] = r * 64 + (((ks * 4 + ls) ^ (r & 7)) * 8);
    }

    STAGE(0, 0);
    STAGE(1, 1);

    #pragma unroll
    for (int kt = 0; kt < NT; ++kt) {
        if (kt < NT - 1) asm volatile("s_waitcnt vmcnt(6)" ::: "memory");
        else             asm volatile("s_waitcnt vmcnt(0)" ::: "memory");
        __builtin_amdgcn_s_barrier();
        if (kt + 2 < NT) STAGE(kt + 2, (kt + 2) % 3);

        const int cb = kt % 3;
        bf16x8 af[4][2], bfv[2][2];
        #pragma unroll
        for (int mi = 0; mi < 4; ++mi)
            #pragma unroll
            for (int ks = 0; ks < 2; ++ks)
                af[mi][ks] = *(const bf16x8*)&As[cb][offA[mi][ks]];
        #pragma unroll
        for (int ni = 0; ni < 2; ++ni)
            #pragma unroll
            for (int ks = 0; ks < 2; ++ks)
                bfv[ni][ks] = *(const bf16x8*)&Bs[cb][offB[ni][ks]];

        #pragma unroll
        for (int mi = 0; mi < 4; ++mi)
            #pragma unroll
            for (int ni = 0; ni < 2; ++ni)
                #pragma unroll
                for (int ks = 0; ks < 2; ++ks)
                    acc[mi][ni] = __builtin_amdgcn_mfma_f32_16x16x32_bf16(af[mi][ks], bfv[ni][ks], acc[mi][ni], 0, 0, 0);
    }

    // C/D layout (m89): col = lane&15, row = (lane>>4)*4 + j
    #pragma unroll
    for (int mi = 0; mi < 4; ++mi) {
        const int row0 = bm + wr * 64 + mi * 16 + ls * 4;
        #pragma unroll
        for (int ni = 0; ni < 2; ++ni) {
            const int col = bn + wc * 32 + ni * 16 + lr;
            const float bv = bias ? bias[col] : 0.0f;
            #pragma unroll
            for (int j = 0; j < 4; ++j) {
                const float v = acc[mi][ni][j] + bv;
                if (MODE == 0) {
                    ((float*)Cout)[(size_t)(row0 + j) * N + col] = v;
                } else if (MODE == 1) {
                    ((unsigned short*)Cout)[(size_t)(row0 + j) * N + col] = f2bf(v);
                } else {
                    unsigned short* dst = (col < 512) ? (unsigned short*)Cout
                                                      : (unsigned short*)Cout2;
                    const int c2 = (col < 512) ? col : col - 512;
                    dst[(size_t)(row0 + j) * 512 + c2] = f2bf(v);
                }
            }
        }
    }
}

// ---------------------------------------------------------------------------
// Fused softmax + rolling dynamic conv (proven R9 version).
// Block = (4 consecutive t, one b), 64 threads (1 wave).
// ---------------------------------------------------------------------------
__global__ __launch_bounds__(64) void dynconv_fused(const unsigned short* __restrict__ hb,
                                                    const unsigned short* __restrict__ lgb,
                                                    unsigned short* __restrict__ cvb) {
    __shared__ float w_s[64][33];

    const int bid = blockIdx.x;
    const int u   = (bid & 7) * 256 + (bid >> 3);   // 2048 % 8 == 0, bijective
    const int tg  = u >> 2;
    const int b   = u & 3;
    const int t0  = tg * 4;
    const int tid = threadIdx.x;

    {
        const int dt = tid >> 4, hd = tid & 15;
        const unsigned short* lp = lgb + (size_t)((t0 + dt) * BB + b) * NPAD + hd * KK;
        float e[KK];
        float mx = -1e30f;
        #pragma unroll
        for (int k = 0; k < KK; ++k) { e[k] = bf2f(lp[k]); mx = fmaxf(mx, e[k]); }
        float sm = 0.f;
        #pragma unroll
        for (int k = 0; k < KK; ++k) { e[k] = __expf(e[k] - mx); sm += e[k]; }
        const float inv = 1.f / sm;
        #pragma unroll
        for (int k = 0; k < KK; ++k) w_s[tid][k] = e[k] * inv;
    }
    __syncthreads();

    const int c0 = tid * 8;
    const int hd = tid >> 2;
    float acc[4][8] = {};
    #pragma unroll
    for (int j = 0; j < 34; ++j) {
        const int tt = t0 - PP + j;
        if ((unsigned)tt >= TT) continue;
        const ushort8 hv = *(const ushort8*)&hb[(size_t)((tt * BB + b) * CC) + c0];
        float hf[8];
        #pragma unroll
        for (int cc = 0; cc < 8; ++cc) hf[cc] = bf2f(hv[cc]);
        #pragma unroll
        for (int dt = 0; dt < 4; ++dt) {
            const int k = j - dt;
            if (k < 0 || k >= KK) continue;
            const float wk = w_s[dt * 16 + hd][k];
            #pragma unroll
            for (int cc = 0; cc < 8; ++cc) acc[dt][cc] = fmaf(hf[cc], wk, acc[dt][cc]);
        }
    }
    #pragma unroll
    for (int dt = 0; dt < 4; ++dt) {
        ushort8 o;
        #pragma unroll
        for (int cc = 0; cc < 8; ++cc) o[cc] = f2bf(acc[dt][cc]);
        *(ushort8*)&cvb[(size_t)(((t0 + dt) * BB + b) * CC) + c0] = o;
    }
}

extern "C" void kernel_launch(void* const* d_in, const int* in_sizes, int n_in,
                              void* d_out, int out_size, void* d_ws, size_t ws_size,
                              hipStream_t stream) {
    const float* x  = (const float*)d_in[0];
    const float* W1 = (const float*)d_in[1];
    const float* b1 = (const float*)d_in[2];
    const float* Wl = (const float*)d_in[3];
    const float* W2 = (const float*)d_in[4];
    const float* b2 = (const float*)d_in[5];
    float* out = (float*)d_out;

    // workspace layout
    unsigned short* xb    = (unsigned short*)d_ws;            // 8 MB
    unsigned short* hb    = xb  + (size_t)MM * CC;            // 8 MB
    unsigned short* cvb   = hb  + (size_t)MM * CC;            // 8 MB
    unsigned short* lgb   = cvb + (size_t)MM * CC;            // 8 MB
    unsigned short* Wcomb = lgb + (size_t)MM * CC;            // 1 MB  [1024][512]
    unsigned short* Wlb   = Wcomb + (size_t)1024 * CC;        // 0.5 MB (padded)
    unsigned short* W1t   = Wlb + (size_t)NPAD * CC;          // 0.5 MB
    unsigned short* W2b   = W1t + (size_t)CC * CC;            // 0.5 MB
    float*          biasc = (float*)(W2b + (size_t)CC * CC);  // 4 KB

    const int nxc = MM * CC;           // 4194304

    cast_x<<<nxc / 1024, 256, 0, stream>>>(x, xb);
    cast_weights<<<768, 256, 0, stream>>>(W1, Wl, W2, Wcomb, Wlb, W2b);
    transpose_W1<<<dim3(8, 8), 256, 0, stream>>>(W1, W1t);
    make_bias<<<8, 256, 0, stream>>>(b1, Wl, biasc);

    // Wlp = Wl @ W1  (bf16, into Wcomb rows 512..1023): A=Wlb, B=W1t
    gemm_nt_mfma<1><<<32, 256, 0, stream>>>(Wlb, W1t, nullptr,
                                            Wcomb + (size_t)512 * CC, nullptr, CC, 8);
    // fused: [h | logits] = x @ [W1 | Wlp]^T + [b1 | Wl@b1]
    gemm_nt_mfma<2><<<1024, 256, 0, stream>>>(xb, Wcomb, biasc, hb, lgb, 1024, 16);
    // softmax + rolling dynamic conv
    dynconv_fused<<<TT * BB / 4, 64, 0, stream>>>(hb, lgb, cvb);
    // out = cv @ W2^T + b2
    gemm_nt_mfma<0><<<512, 256, 0, stream>>>(cvb, W2b, b2, out, nullptr, CC, 8);
}

// Round 11
// 62.881 us; speedup vs baseline: 1.1582x; 1.1582x over previous
//
#include <hip/hip_runtime.h>
#include <hip/hip_bf16.h>

// Problem constants
#define TT 2048
#define BB 4
#define CC 512
#define HH 16
#define KK 31
#define PP 15
#define MM (TT*BB)      // 8192 rows
#define NPAD 512        // HK=496 padded to 512 (pad rows of Wl are zero)

typedef __bf16 bf16x8 __attribute__((ext_vector_type(8)));
typedef float f32x4 __attribute__((ext_vector_type(4)));
typedef unsigned short ushort8 __attribute__((ext_vector_type(8)));
typedef unsigned short ushort4v __attribute__((ext_vector_type(4)));

__device__ __forceinline__ float bf2f(unsigned short u) {
    return __uint_as_float(((unsigned int)u) << 16);
}
__device__ __forceinline__ unsigned short f2bf(float f) {
    unsigned int x = __float_as_uint(f);
    x += 0x7fffu + ((x >> 16) & 1u);
    return (unsigned short)(x >> 16);
}

// ---------------------------------------------------------------------------
// cast fp32 -> bf16 for x (4 elems/thread)
// ---------------------------------------------------------------------------
__global__ __launch_bounds__(256) void cast_x(const float* __restrict__ src,
                                              unsigned short* __restrict__ dst) {
    const int i = (blockIdx.x * 256 + threadIdx.x) * 4;
    const float4 v = *(const float4*)&src[i];
    ushort4v o = { f2bf(v.x), f2bf(v.y), f2bf(v.z), f2bf(v.w) };
    *(ushort4v*)&dst[i] = o;
}

// ---------------------------------------------------------------------------
// cast all three weight matrices in one dispatch (768 blocks x 1024 elems).
// Wl rows 496..511 are zero-padded.
// ---------------------------------------------------------------------------
__global__ __launch_bounds__(256) void cast_weights(const float* __restrict__ W1,
                                                    const float* __restrict__ Wl,
                                                    const float* __restrict__ W2,
                                                    unsigned short* __restrict__ W1b,
                                                    unsigned short* __restrict__ Wlb,
                                                    unsigned short* __restrict__ W2b) {
    const int b = blockIdx.x;
    const int i = (b & 255) * 1024 + threadIdx.x * 4;
    const float* src;
    unsigned short* dst;
    int n_src = 262144;
    if (b < 256)      { src = W1; dst = W1b; }
    else if (b < 512) { src = Wl; dst = Wlb; n_src = HH * KK * CC; }
    else              { src = W2; dst = W2b; }
    ushort4v o = {0, 0, 0, 0};
    if (i < n_src) {
        const float4 v = *(const float4*)&src[i];
        o[0] = f2bf(v.x); o[1] = f2bf(v.y); o[2] = f2bf(v.z); o[3] = f2bf(v.w);
    }
    *(ushort4v*)&dst[i] = o;
}

// ---------------------------------------------------------------------------
// bf16 MFMA GEMM-NT, 3-stage counted-vmcnt pipeline, BK=32 for occupancy:
// C[m,n] = sum_k A[m,k]*B[n,k] (+bias[n]); K fixed 512 (NT=16 x BK=32).
// 128x64 tile, 256 thr = 4 waves (2x2), each wave 64x32 out.
// LDS 3 x 12 KB = 36 KB -> 4 blocks/CU (16 waves/CU: 2x R9's latency hiding).
// Per iter kt: {vmcnt(3); s_barrier; STAGE(kt+2); compute buf kt%3}.
// Swizzle (rows are 64 B = half a bank span): LDS slot p at row r holds
// global slot (p - (r>>1))&3; read uses p = (ls + (r>>1))&3 -> lanes walk
// 8 distinct 16B slots per 128 B span (2-way, free per m136).
// ---------------------------------------------------------------------------
#define GBM 128
#define GBN 64
#define GBK 32
#define KC  512
#define NT  16

#define STAGE(kt, buf)                                                                         \
    do {                                                                                       \
        const int k0_ = (kt) * GBK;                                                            \
        _Pragma("unroll")                                                                      \
        for (int j = 0; j < 2; ++j)                                                            \
            __builtin_amdgcn_global_load_lds(                                                  \
                (const __attribute__((address_space(1))) void*)(gA[j] + k0_),                  \
                (__attribute__((address_space(3))) void*)(&As[buf][0] + j * 2048 + wv * 512),  \
                16, 0, 0);                                                                     \
        __builtin_amdgcn_global_load_lds(                                                      \
            (const __attribute__((address_space(1))) void*)(gB0 + k0_),                        \
            (__attribute__((address_space(3))) void*)(&Bs[buf][0] + wv * 512),                 \
            16, 0, 0);                                                                         \
    } while (0)

template<bool OUT_BF16>
__global__ __launch_bounds__(256, 4) void gemm_nt_mfma(const unsigned short* __restrict__ A,
                                                       const unsigned short* __restrict__ B,
                                                       const float* __restrict__ bias,
                                                       void* __restrict__ Cout,
                                                       int N, int nn) {
    __shared__ short As[3][GBM * GBK];   // 3 x 8 KB
    __shared__ short Bs[3][GBN * GBK];   // 3 x 4 KB

    const int tid = threadIdx.x;
    const int l   = tid & 63;
    const int wv  = tid >> 6;      // wave 0..3
    const int wr  = wv >> 1;       // wave row (0..1) -> 64 rows
    const int wc  = wv & 1;        // wave col (0..1) -> 32 cols

    // chunked XCD swizzle; consecutive s share A panel in the XCD's L2
    const int s  = (blockIdx.x & 7) * (gridDim.x >> 3) + (blockIdx.x >> 3);
    const int bm = (s / nn) * GBM;
    const int bn = (s % nn) * GBN;

    // Staging: A tile 128 rows x 4 slots(16B) = 512 slots = 2 rounds x 256thr;
    // B tile 64 x 4 = 256 slots = 1 round. Linear LDS dest; global source
    // slot = (p - (r>>1)) & 3 (inverse of the read rotation).
    const unsigned short* gA[2];
    #pragma unroll
    for (int j = 0; j < 2; ++j) {
        const int idx16 = j * 256 + tid;
        const int r  = idx16 >> 2;
        const int sl = ((idx16 & 3) - (r >> 1)) & 3;
        gA[j] = A + (size_t)(bm + r) * KC + sl * 8;
    }
    const int rB  = tid >> 2;
    const int slB = ((tid & 3) - (rB >> 1)) & 3;
    const unsigned short* gB0 = B + (size_t)(bn + rB) * KC + slB * 8;

    f32x4 acc[4][2] = {};

    const int lr = l & 15;     // fragment row-within-16
    const int ls = l >> 4;     // k-slot 0..3 (8 bf16 each)
    int offA[4], offB[2];
    #pragma unroll
    for (int mi = 0; mi < 4; ++mi) {
        const int r = wr * 64 + mi * 16 + lr;
        offA[mi] = r * 32 + (((ls + (r >> 1)) & 3) * 8);
    }
    #pragma unroll
    for (int ni = 0; ni < 2; ++ni) {
        const int r = wc * 32 + ni * 16 + lr;
        offB[ni] = r * 32 + (((ls + (r >> 1)) & 3) * 8);
    }

    // prologue: stage tiles 0,1 (6 loads in flight per wave-slot)
    STAGE(0, 0);
    STAGE(1, 1);

    #pragma unroll
    for (int kt = 0; kt < NT; ++kt) {
        // (a) tile kt resident; tile kt+1's 3 loads stay in flight
        if (kt < NT - 1) asm volatile("s_waitcnt vmcnt(3)" ::: "memory");
        else             asm volatile("s_waitcnt vmcnt(0)" ::: "memory");
        // (b) all waves: tile kt loaded, compute(kt-1) done everywhere
        __builtin_amdgcn_s_barrier();
        // (c) prefetch tile kt+2 (overwrites buf[(kt-1)%3], safe post-barrier)
        if (kt + 2 < NT) STAGE(kt + 2, (kt + 2) % 3);

        // (d) compute on buf kt%3
        const int cb = kt % 3;
        bf16x8 af[4], bfv[2];
        #pragma unroll
        for (int mi = 0; mi < 4; ++mi) af[mi] = *(const bf16x8*)&As[cb][offA[mi]];
        #pragma unroll
        for (int ni = 0; ni < 2; ++ni) bfv[ni] = *(const bf16x8*)&Bs[cb][offB[ni]];

        #pragma unroll
        for (int mi = 0; mi < 4; ++mi)
            #pragma unroll
            for (int ni = 0; ni < 2; ++ni)
                acc[mi][ni] = __builtin_amdgcn_mfma_f32_16x16x32_bf16(af[mi], bfv[ni], acc[mi][ni], 0, 0, 0);
    }

    // C/D layout (m89): col = lane&15, row = (lane>>4)*4 + j
    #pragma unroll
    for (int mi = 0; mi < 4; ++mi) {
        const int row0 = bm + wr * 64 + mi * 16 + ls * 4;
        #pragma unroll
        for (int ni = 0; ni < 2; ++ni) {
            const int col = bn + wc * 32 + ni * 16 + lr;
            const float bv = bias ? bias[col] : 0.0f;
            #pragma unroll
            for (int j = 0; j < 4; ++j) {
                const float v = acc[mi][ni][j] + bv;
                if (OUT_BF16)
                    ((unsigned short*)Cout)[(size_t)(row0 + j) * N + col] = f2bf(v);
                else
                    ((float*)Cout)[(size_t)(row0 + j) * N + col] = v;
            }
        }
    }
}

// ---------------------------------------------------------------------------
// Fused softmax + rolling dynamic conv (proven R9 version).
// Block = (4 consecutive t, one b), 64 threads (1 wave).
// ---------------------------------------------------------------------------
__global__ __launch_bounds__(64) void dynconv_fused(const unsigned short* __restrict__ hb,
                                                    const unsigned short* __restrict__ lgb,
                                                    unsigned short* __restrict__ cvb) {
    __shared__ float w_s[64][33];

    const int bid = blockIdx.x;
    const int u   = (bid & 7) * 256 + (bid >> 3);   // 2048 % 8 == 0, bijective
    const int tg  = u >> 2;
    const int b   = u & 3;
    const int t0  = tg * 4;
    const int tid = threadIdx.x;

    {
        const int dt = tid >> 4, hd = tid & 15;
        const unsigned short* lp = lgb + (size_t)((t0 + dt) * BB + b) * NPAD + hd * KK;
        float e[KK];
        float mx = -1e30f;
        #pragma unroll
        for (int k = 0; k < KK; ++k) { e[k] = bf2f(lp[k]); mx = fmaxf(mx, e[k]); }
        float sm = 0.f;
        #pragma unroll
        for (int k = 0; k < KK; ++k) { e[k] = __expf(e[k] - mx); sm += e[k]; }
        const float inv = 1.f / sm;
        #pragma unroll
        for (int k = 0; k < KK; ++k) w_s[tid][k] = e[k] * inv;
    }
    __syncthreads();

    const int c0 = tid * 8;
    const int hd = tid >> 2;
    float acc[4][8] = {};
    #pragma unroll
    for (int j = 0; j < 34; ++j) {
        const int tt = t0 - PP + j;
        if ((unsigned)tt >= TT) continue;
        const ushort8 hv = *(const ushort8*)&hb[(size_t)((tt * BB + b) * CC) + c0];
        float hf[8];
        #pragma unroll
        for (int cc = 0; cc < 8; ++cc) hf[cc] = bf2f(hv[cc]);
        #pragma unroll
        for (int dt = 0; dt < 4; ++dt) {
            const int k = j - dt;
            if (k < 0 || k >= KK) continue;
            const float wk = w_s[dt * 16 + hd][k];
            #pragma unroll
            for (int cc = 0; cc < 8; ++cc) acc[dt][cc] = fmaf(hf[cc], wk, acc[dt][cc]);
        }
    }
    #pragma unroll
    for (int dt = 0; dt < 4; ++dt) {
        ushort8 o;
        #pragma unroll
        for (int cc = 0; cc < 8; ++cc) o[cc] = f2bf(acc[dt][cc]);
        *(ushort8*)&cvb[(size_t)(((t0 + dt) * BB + b) * CC) + c0] = o;
    }
}

extern "C" void kernel_launch(void* const* d_in, const int* in_sizes, int n_in,
                              void* d_out, int out_size, void* d_ws, size_t ws_size,
                              hipStream_t stream) {
    const float* x  = (const float*)d_in[0];
    const float* W1 = (const float*)d_in[1];
    const float* b1 = (const float*)d_in[2];
    const float* Wl = (const float*)d_in[3];
    const float* W2 = (const float*)d_in[4];
    const float* b2 = (const float*)d_in[5];
    float* out = (float*)d_out;

    // workspace layout (all bf16 except out)
    unsigned short* xb  = (unsigned short*)d_ws;             // 8 MB
    unsigned short* hb  = xb  + (size_t)MM * CC;             // 8 MB
    unsigned short* cvb = hb  + (size_t)MM * CC;             // 8 MB
    unsigned short* W1b = cvb + (size_t)MM * CC;             // 0.5 MB
    unsigned short* Wlb = W1b + (size_t)CC * CC;             // 0.5 MB (padded)
    unsigned short* W2b = Wlb + (size_t)NPAD * CC;           // 0.5 MB
    unsigned short* lgb = W2b + (size_t)CC * CC;             // 8 MB bf16 logits

    const int nxc = MM * CC;           // 4194304

    cast_x<<<nxc / 1024, 256, 0, stream>>>(x, xb);
    cast_weights<<<768, 256, 0, stream>>>(W1, Wl, W2, W1b, Wlb, W2b);

    const int nblk = (MM / GBM) * (CC / GBN);   // 64 * 8 = 512

    // 1) h = x @ W1^T + b1   (bf16 out)
    gemm_nt_mfma<true><<<nblk, 256, 0, stream>>>(xb, W1b, b1, hb, CC, CC / GBN);
    // 2) logits = h @ Wl^T   (bf16 out, padded N)
    gemm_nt_mfma<true><<<nblk, 256, 0, stream>>>(hb, Wlb, nullptr, lgb, NPAD, NPAD / GBN);
    // 3+4) fused softmax + rolling dynamic conv (bf16 out)
    dynconv_fused<<<TT * BB / 4, 64, 0, stream>>>(hb, lgb, cvb);
    // 5) out = cv @ W2^T + b2  (fp32 out)
    gemm_nt_mfma<false><<<nblk, 256, 0, stream>>>(cvb, W2b, b2, out, CC, CC / GBN);
}

// Round 12
// 52.089 us; speedup vs baseline: 1.3982x; 1.2072x over previous
//
#include <hip/hip_runtime.h>
#include <hip/hip_bf16.h>

// Problem constants
#define TT 2048
#define BB 4
#define CC 512
#define HH 16
#define KK 31
#define PP 15
#define MM (TT*BB)      // 8192 rows
#define NPAD 512        // HK=496 padded to 512 (pad rows of Wl are zero)

typedef __bf16 bf16x8 __attribute__((ext_vector_type(8)));
typedef float f32x4 __attribute__((ext_vector_type(4)));
typedef unsigned short ushort8 __attribute__((ext_vector_type(8)));
typedef unsigned short ushort4v __attribute__((ext_vector_type(4)));

__device__ __forceinline__ float bf2f(unsigned short u) {
    return __uint_as_float(((unsigned int)u) << 16);
}
__device__ __forceinline__ unsigned short f2bf(float f) {
    unsigned int x = __float_as_uint(f);
    x += 0x7fffu + ((x >> 16) & 1u);
    return (unsigned short)(x >> 16);
}

// ---------------------------------------------------------------------------
// single cast dispatch: blocks 0..4095 cast x (1024 elems each);
// blocks 4096..4863 cast W1/Wl/W2 (Wl zero-padded to 512 rows).
// ---------------------------------------------------------------------------
__global__ __launch_bounds__(256) void cast_all(const float* __restrict__ x,
                                                const float* __restrict__ W1,
                                                const float* __restrict__ Wl,
                                                const float* __restrict__ W2,
                                                unsigned short* __restrict__ xb,
                                                unsigned short* __restrict__ W1b,
                                                unsigned short* __restrict__ Wlb,
                                                unsigned short* __restrict__ W2b) {
    const int b = blockIdx.x;
    if (b < 4096) {
        const int i = b * 1024 + threadIdx.x * 4;
        const float4 v = *(const float4*)&x[i];
        ushort4v o = { f2bf(v.x), f2bf(v.y), f2bf(v.z), f2bf(v.w) };
        *(ushort4v*)&xb[i] = o;
        return;
    }
    const int bb = b - 4096;                 // 0..767
    const int i = (bb & 255) * 1024 + threadIdx.x * 4;
    const float* src;
    unsigned short* dst;
    int n_src = 262144;
    if (bb < 256)      { src = W1; dst = W1b; }
    else if (bb < 512) { src = Wl; dst = Wlb; n_src = HH * KK * CC; }
    else               { src = W2; dst = W2b; }
    ushort4v o = {0, 0, 0, 0};
    if (i < n_src) {
        const float4 v = *(const float4*)&src[i];
        o[0] = f2bf(v.x); o[1] = f2bf(v.y); o[2] = f2bf(v.z); o[3] = f2bf(v.w);
    }
    *(ushort4v*)&dst[i] = o;
}

// ---------------------------------------------------------------------------
// bf16 MFMA GEMM-NT, 3-stage pipeline with counted vmcnt (R9-proven config):
// C[m,n] = sum_k A[m,k]*B[n,k] (+bias[n]); K fixed 512 (NT=8 x BK=64).
// 128x64 tile, 256 thr = 4 waves (2x2), each wave 64x32 out.
// Per iter t: {vmcnt(6); s_barrier; issue stage(t+2); ds_read+MFMA on buf t%3}.
// vmcnt never drains to 0 in-loop -> prefetch stays in flight across barriers.
// LDS 3*(16+8)=72 KB -> 2 blocks/CU. 512 blocks. Swizzle slot^=(row&7).
// ---------------------------------------------------------------------------
#define GBM 128
#define GBN 64
#define GBK 64
#define KC  512
#define NT  8

#define STAGE(kt, buf)                                                                         \
    do {                                                                                       \
        const int k0_ = (kt) * GBK;                                                            \
        _Pragma("unroll")                                                                      \
        for (int j = 0; j < 4; ++j)                                                            \
            __builtin_amdgcn_global_load_lds(                                                  \
                (const __attribute__((address_space(1))) void*)(gA[j] + k0_),                  \
                (__attribute__((address_space(3))) void*)(&As[buf][0] + j * 2048 + wv * 512),  \
                16, 0, 0);                                                                     \
        _Pragma("unroll")                                                                      \
        for (int j = 0; j < 2; ++j)                                                            \
            __builtin_amdgcn_global_load_lds(                                                  \
                (const __attribute__((address_space(1))) void*)(gB[j] + k0_),                  \
                (__attribute__((address_space(3))) void*)(&Bs[buf][0] + j * 2048 + wv * 512),  \
                16, 0, 0);                                                                     \
    } while (0)

template<bool OUT_BF16>
__global__ __launch_bounds__(256, 2) void gemm_nt_mfma(const unsigned short* __restrict__ A,
                                                       const unsigned short* __restrict__ B,
                                                       const float* __restrict__ bias,
                                                       void* __restrict__ Cout,
                                                       int N, int nn) {
    __shared__ short As[3][GBM * GBK];   // 3 x 16 KB
    __shared__ short Bs[3][GBN * GBK];   // 3 x 8 KB

    const int tid = threadIdx.x;
    const int l   = tid & 63;
    const int wv  = tid >> 6;      // wave 0..3
    const int wr  = wv >> 1;       // wave row (0..1) -> 64 rows
    const int wc  = wv & 1;        // wave col (0..1) -> 32 cols

    // chunked XCD swizzle; consecutive s share A panel in the XCD's L2
    const int s  = (blockIdx.x & 7) * (gridDim.x >> 3) + (blockIdx.x >> 3);
    const int bm = (s / nn) * GBM;
    const int bn = (s % nn) * GBN;

    // Staging: A tile 128 rows x 8 slots(16B) = 4 rounds x 256 thr; B tile
    // 64 x 8 = 2 rounds. Linear LDS dest; source slot pre-swizzled
    // slot' = slot ^ (row&7) (involution, matches swizzled ds_read).
    const unsigned short* gA[4];
    const unsigned short* gB[2];
    #pragma unroll
    for (int j = 0; j < 4; ++j) {
        const int idx16 = j * 256 + tid;
        const int r  = idx16 >> 3;
        const int sl = (idx16 & 7) ^ (r & 7);
        gA[j] = A + (size_t)(bm + r) * KC + sl * 8;
    }
    #pragma unroll
    for (int j = 0; j < 2; ++j) {
        const int idx16 = j * 256 + tid;
        const int r  = idx16 >> 3;
        const int sl = (idx16 & 7) ^ (r & 7);
        gB[j] = B + (size_t)(bn + r) * KC + sl * 8;
    }

    f32x4 acc[4][2] = {};

    const int lr = l & 15;     // fragment row-within-16
    const int ls = l >> 4;     // k-slot (8 bf16 each)
    int offA[4][2], offB[2][2];
    #pragma unroll
    for (int mi = 0; mi < 4; ++mi) {
        const int r = wr * 64 + mi * 16 + lr;
        #pragma unroll
        for (int ks = 0; ks < 2; ++ks)
            offA[mi][ks] = r * 64 + (((ks * 4 + ls) ^ (r & 7)) * 8);
    }
    #pragma unroll
    for (int ni = 0; ni < 2; ++ni) {
        const int r = wc * 32 + ni * 16 + lr;
        #pragma unroll
        for (int ks = 0; ks < 2; ++ks)
            offB[ni][ks] = r * 64 + (((ks * 4 + ls) ^ (r & 7)) * 8);
    }

    // prologue: stage tiles 0,1 (12 loads in flight per wave)
    STAGE(0, 0);
    STAGE(1, 1);

    #pragma unroll
    for (int kt = 0; kt < NT; ++kt) {
        // (a) wait: tile kt resident (keep later tiles in flight)
        if (kt < NT - 1) asm volatile("s_waitcnt vmcnt(6)" ::: "memory");
        else             asm volatile("s_waitcnt vmcnt(0)" ::: "memory");
        // (b) all waves: tile kt loaded everywhere, compute(kt-1) done everywhere
        __builtin_amdgcn_s_barrier();
        // (c) prefetch tile kt+2 (overwrites buf[(kt-1)%3], safe after barrier)
        if (kt + 2 < NT) STAGE(kt + 2, (kt + 2) % 3);

        // (d) compute on buf kt%3
        const int cb = kt % 3;
        bf16x8 af[4][2], bfv[2][2];
        #pragma unroll
        for (int mi = 0; mi < 4; ++mi)
            #pragma unroll
            for (int ks = 0; ks < 2; ++ks)
                af[mi][ks] = *(const bf16x8*)&As[cb][offA[mi][ks]];
        #pragma unroll
        for (int ni = 0; ni < 2; ++ni)
            #pragma unroll
            for (int ks = 0; ks < 2; ++ks)
                bfv[ni][ks] = *(const bf16x8*)&Bs[cb][offB[ni][ks]];

        #pragma unroll
        for (int mi = 0; mi < 4; ++mi)
            #pragma unroll
            for (int ni = 0; ni < 2; ++ni)
                #pragma unroll
                for (int ks = 0; ks < 2; ++ks)
                    acc[mi][ni] = __builtin_amdgcn_mfma_f32_16x16x32_bf16(af[mi][ks], bfv[ni][ks], acc[mi][ni], 0, 0, 0);
    }

    // C/D layout (m89): col = lane&15, row = (lane>>4)*4 + j
    #pragma unroll
    for (int mi = 0; mi < 4; ++mi) {
        const int row0 = bm + wr * 64 + mi * 16 + ls * 4;
        #pragma unroll
        for (int ni = 0; ni < 2; ++ni) {
            const int col = bn + wc * 32 + ni * 16 + lr;
            const float bv = bias ? bias[col] : 0.0f;
            #pragma unroll
            for (int j = 0; j < 4; ++j) {
                const float v = acc[mi][ni][j] + bv;
                if (OUT_BF16)
                    ((unsigned short*)Cout)[(size_t)(row0 + j) * N + col] = f2bf(v);
                else
                    ((float*)Cout)[(size_t)(row0 + j) * N + col] = v;
            }
        }
    }
}

// ---------------------------------------------------------------------------
// Fused softmax + rolling dynamic conv (proven R9 version).
// Block = (4 consecutive t, one b), 64 threads (1 wave).
// ---------------------------------------------------------------------------
__global__ __launch_bounds__(64) void dynconv_fused(const unsigned short* __restrict__ hb,
                                                    const unsigned short* __restrict__ lgb,
                                                    unsigned short* __restrict__ cvb) {
    __shared__ float w_s[64][33];

    const int bid = blockIdx.x;
    const int u   = (bid & 7) * 256 + (bid >> 3);   // 2048 % 8 == 0, bijective
    const int tg  = u >> 2;
    const int b   = u & 3;
    const int t0  = tg * 4;
    const int tid = threadIdx.x;

    {
        const int dt = tid >> 4, hd = tid & 15;
        const unsigned short* lp = lgb + (size_t)((t0 + dt) * BB + b) * NPAD + hd * KK;
        float e[KK];
        float mx = -1e30f;
        #pragma unroll
        for (int k = 0; k < KK; ++k) { e[k] = bf2f(lp[k]); mx = fmaxf(mx, e[k]); }
        float sm = 0.f;
        #pragma unroll
        for (int k = 0; k < KK; ++k) { e[k] = __expf(e[k] - mx); sm += e[k]; }
        const float inv = 1.f / sm;
        #pragma unroll
        for (int k = 0; k < KK; ++k) w_s[tid][k] = e[k] * inv;
    }
    __syncthreads();

    const int c0 = tid * 8;
    const int hd = tid >> 2;
    float acc[4][8] = {};
    #pragma unroll
    for (int j = 0; j < 34; ++j) {
        const int tt = t0 - PP + j;
        if ((unsigned)tt >= TT) continue;
        const ushort8 hv = *(const ushort8*)&hb[(size_t)((tt * BB + b) * CC) + c0];
        float hf[8];
        #pragma unroll
        for (int cc = 0; cc < 8; ++cc) hf[cc] = bf2f(hv[cc]);
        #pragma unroll
        for (int dt = 0; dt < 4; ++dt) {
            const int k = j - dt;
            if (k < 0 || k >= KK) continue;
            const float wk = w_s[dt * 16 + hd][k];
            #pragma unroll
            for (int cc = 0; cc < 8; ++cc) acc[dt][cc] = fmaf(hf[cc], wk, acc[dt][cc]);
        }
    }
    #pragma unroll
    for (int dt = 0; dt < 4; ++dt) {
        ushort8 o;
        #pragma unroll
        for (int cc = 0; cc < 8; ++cc) o[cc] = f2bf(acc[dt][cc]);
        *(ushort8*)&cvb[(size_t)(((t0 + dt) * BB + b) * CC) + c0] = o;
    }
}

extern "C" void kernel_launch(void* const* d_in, const int* in_sizes, int n_in,
                              void* d_out, int out_size, void* d_ws, size_t ws_size,
                              hipStream_t stream) {
    const float* x  = (const float*)d_in[0];
    const float* W1 = (const float*)d_in[1];
    const float* b1 = (const float*)d_in[2];
    const float* Wl = (const float*)d_in[3];
    const float* W2 = (const float*)d_in[4];
    const float* b2 = (const float*)d_in[5];
    float* out = (float*)d_out;

    // workspace layout (all bf16 except out)
    unsigned short* xb  = (unsigned short*)d_ws;             // 8 MB
    unsigned short* hb  = xb  + (size_t)MM * CC;             // 8 MB
    unsigned short* cvb = hb  + (size_t)MM * CC;             // 8 MB
    unsigned short* W1b = cvb + (size_t)MM * CC;             // 0.5 MB
    unsigned short* Wlb = W1b + (size_t)CC * CC;             // 0.5 MB (padded)
    unsigned short* W2b = Wlb + (size_t)NPAD * CC;           // 0.5 MB
    unsigned short* lgb = W2b + (size_t)CC * CC;             // 8 MB bf16 logits

    // single cast dispatch (x + all weights)
    cast_all<<<4096 + 768, 256, 0, stream>>>(x, W1, Wl, W2, xb, W1b, Wlb, W2b);

    const int nblk = (MM / GBM) * (CC / GBN);   // 64 * 8 = 512

    // 1) h = x @ W1^T + b1   (bf16 out)
    gemm_nt_mfma<true><<<nblk, 256, 0, stream>>>(xb, W1b, b1, hb, CC, CC / GBN);
    // 2) logits = h @ Wl^T   (bf16 out, padded N)
    gemm_nt_mfma<true><<<nblk, 256, 0, stream>>>(hb, Wlb, nullptr, lgb, NPAD, NPAD / GBN);
    // 3+4) fused softmax + rolling dynamic conv (bf16 out)
    dynconv_fused<<<TT * BB / 4, 64, 0, stream>>>(hb, lgb, cvb);
    // 5) out = cv @ W2^T + b2  (fp32 out)
    gemm_nt_mfma<false><<<nblk, 256, 0, stream>>>(cvb, W2b, b2, out, CC, CC / GBN);
}

// Round 13
// 50.362 us; speedup vs baseline: 1.4461x; 1.0343x over previous
//
#include <hip/hip_runtime.h>
#include <hip/hip_bf16.h>

// Problem constants
#define TT 2048
#define BB 4
#define CC 512
#define HH 16
#define KK 31
#define PP 15
#define MM (TT*BB)      // 8192 rows
#define NPAD 512        // HK=496 padded to 512 (pad rows of Wl are zero)

typedef __bf16 bf16x8 __attribute__((ext_vector_type(8)));
typedef float f32x4 __attribute__((ext_vector_type(4)));
typedef unsigned short ushort8 __attribute__((ext_vector_type(8)));
typedef unsigned short ushort4v __attribute__((ext_vector_type(4)));

__device__ __forceinline__ float bf2f(unsigned short u) {
    return __uint_as_float(((unsigned int)u) << 16);
}
__device__ __forceinline__ unsigned short f2bf(float f) {
    unsigned int x = __float_as_uint(f);
    x += 0x7fffu + ((x >> 16) & 1u);
    return (unsigned short)(x >> 16);
}

// ---------------------------------------------------------------------------
// single cast dispatch: blocks 0..4095 cast x (1024 elems each);
// blocks 4096..4863 cast W1/Wl/W2 (Wl zero-padded to 512 rows).
// ---------------------------------------------------------------------------
__global__ __launch_bounds__(256) void cast_all(const float* __restrict__ x,
                                                const float* __restrict__ W1,
                                                const float* __restrict__ Wl,
                                                const float* __restrict__ W2,
                                                unsigned short* __restrict__ xb,
                                                unsigned short* __restrict__ W1b,
                                                unsigned short* __restrict__ Wlb,
                                                unsigned short* __restrict__ W2b) {
    const int b = blockIdx.x;
    if (b < 4096) {
        const int i = b * 1024 + threadIdx.x * 4;
        const float4 v = *(const float4*)&x[i];
        ushort4v o = { f2bf(v.x), f2bf(v.y), f2bf(v.z), f2bf(v.w) };
        *(ushort4v*)&xb[i] = o;
        return;
    }
    const int bb = b - 4096;                 // 0..767
    const int i = (bb & 255) * 1024 + threadIdx.x * 4;
    const float* src;
    unsigned short* dst;
    int n_src = 262144;
    if (bb < 256)      { src = W1; dst = W1b; }
    else if (bb < 512) { src = Wl; dst = Wlb; n_src = HH * KK * CC; }
    else               { src = W2; dst = W2b; }
    ushort4v o = {0, 0, 0, 0};
    if (i < n_src) {
        const float4 v = *(const float4*)&src[i];
        o[0] = f2bf(v.x); o[1] = f2bf(v.y); o[2] = f2bf(v.z); o[3] = f2bf(v.w);
    }
    *(ushort4v*)&dst[i] = o;
}

// ---------------------------------------------------------------------------
// bf16 MFMA GEMM-NT, 3-stage counted-vmcnt pipeline, 8 WAVES (R12 structure,
// doubled wave-parallelism): C[m,n] = sum_k A[m,k]*B[n,k] (+bias[n]).
// K fixed 512 (NT=8 x BK=64). 128x64 tile, 512 thr = 8 waves (4m x 2n),
// wave-tile 32x32 (2x2 fragments, 8 MFMA + 8 ds_read_b128 per K-step).
// LDS 3*(16+8)=72 KB -> 2 blocks/CU -> 16 waves/CU = 4 waves/SIMD (2x R9).
// Per iter kt: {vmcnt(3); s_barrier; STAGE(kt+2); compute buf kt%3}.
// STAGE = 3 loads/thread (2 A rounds + 1 B round). Swizzle slot^=(row&7).
// ---------------------------------------------------------------------------
#define GBM 128
#define GBN 64
#define GBK 64
#define KC  512
#define NT  8

#define STAGE(kt, buf)                                                                             \
    do {                                                                                           \
        const int k0_ = (kt) * GBK;                                                                \
        _Pragma("unroll")                                                                          \
        for (int j = 0; j < 2; ++j)                                                                \
            __builtin_amdgcn_global_load_lds(                                                      \
                (const __attribute__((address_space(1))) void*)(gA[j] + k0_),                      \
                (__attribute__((address_space(3))) void*)(&As[buf][0] + (j * 512 + wv * 64) * 8),  \
                16, 0, 0);                                                                         \
        __builtin_amdgcn_global_load_lds(                                                          \
            (const __attribute__((address_space(1))) void*)(gB0 + k0_),                            \
            (__attribute__((address_space(3))) void*)(&Bs[buf][0] + wv * 64 * 8),                  \
            16, 0, 0);                                                                             \
    } while (0)

template<bool OUT_BF16>
__global__ __launch_bounds__(512, 4) void gemm_nt_mfma(const unsigned short* __restrict__ A,
                                                       const unsigned short* __restrict__ B,
                                                       const float* __restrict__ bias,
                                                       void* __restrict__ Cout,
                                                       int N, int nn) {
    __shared__ short As[3][GBM * GBK];   // 3 x 16 KB
    __shared__ short Bs[3][GBN * GBK];   // 3 x 8 KB

    const int tid = threadIdx.x;
    const int l   = tid & 63;
    const int wv  = tid >> 6;      // wave 0..7
    const int wr  = wv >> 1;       // wave row (0..3) -> 32 rows each
    const int wc  = wv & 1;        // wave col (0..1) -> 32 cols each

    // chunked XCD swizzle; consecutive s share A panel in the XCD's L2
    const int s  = (blockIdx.x & 7) * (gridDim.x >> 3) + (blockIdx.x >> 3);
    const int bm = (s / nn) * GBM;
    const int bn = (s % nn) * GBN;

    // Staging: A tile 128 rows x 8 slots(16B) = 1024 slots = 2 rounds x 512thr;
    // B tile 64 x 8 = 512 slots = 1 round. Linear LDS dest; source slot
    // pre-swizzled slot' = slot ^ (row&7) (involution, matches ds_read).
    const unsigned short* gA[2];
    #pragma unroll
    for (int j = 0; j < 2; ++j) {
        const int slot = j * 512 + tid;
        const int r  = slot >> 3;
        const int sl = (slot & 7) ^ (r & 7);
        gA[j] = A + (size_t)(bm + r) * KC + sl * 8;
    }
    const int rB  = tid >> 3;
    const int slB = (tid & 7) ^ (rB & 7);
    const unsigned short* gB0 = B + (size_t)(bn + rB) * KC + slB * 8;

    f32x4 acc[2][2] = {};

    const int lr = l & 15;     // fragment row-within-16
    const int ls = l >> 4;     // k-slot (8 bf16 each)
    int offA[2][2], offB[2][2];
    #pragma unroll
    for (int mi = 0; mi < 2; ++mi) {
        const int r = wr * 32 + mi * 16 + lr;
        #pragma unroll
        for (int ks = 0; ks < 2; ++ks)
            offA[mi][ks] = r * 64 + (((ks * 4 + ls) ^ (r & 7)) * 8);
    }
    #pragma unroll
    for (int ni = 0; ni < 2; ++ni) {
        const int r = wc * 32 + ni * 16 + lr;
        #pragma unroll
        for (int ks = 0; ks < 2; ++ks)
            offB[ni][ks] = r * 64 + (((ks * 4 + ls) ^ (r & 7)) * 8);
    }

    // prologue: stage tiles 0,1 (6 loads in flight per wave)
    STAGE(0, 0);
    STAGE(1, 1);

    #pragma unroll
    for (int kt = 0; kt < NT; ++kt) {
        // (a) tile kt resident; tile kt+1's 3 loads stay in flight
        if (kt < NT - 1) asm volatile("s_waitcnt vmcnt(3)" ::: "memory");
        else             asm volatile("s_waitcnt vmcnt(0)" ::: "memory");
        // (b) all waves: tile kt loaded everywhere, compute(kt-1) done
        __builtin_amdgcn_s_barrier();
        // (c) prefetch tile kt+2 (overwrites buf[(kt-1)%3], safe post-barrier)
        if (kt + 2 < NT) STAGE(kt + 2, (kt + 2) % 3);

        // (d) compute on buf kt%3
        const int cb = kt % 3;
        bf16x8 af[2][2], bfv[2][2];
        #pragma unroll
        for (int mi = 0; mi < 2; ++mi)
            #pragma unroll
            for (int ks = 0; ks < 2; ++ks)
                af[mi][ks] = *(const bf16x8*)&As[cb][offA[mi][ks]];
        #pragma unroll
        for (int ni = 0; ni < 2; ++ni)
            #pragma unroll
            for (int ks = 0; ks < 2; ++ks)
                bfv[ni][ks] = *(const bf16x8*)&Bs[cb][offB[ni][ks]];

        #pragma unroll
        for (int mi = 0; mi < 2; ++mi)
            #pragma unroll
            for (int ni = 0; ni < 2; ++ni)
                #pragma unroll
                for (int ks = 0; ks < 2; ++ks)
                    acc[mi][ni] = __builtin_amdgcn_mfma_f32_16x16x32_bf16(af[mi][ks], bfv[ni][ks], acc[mi][ni], 0, 0, 0);
    }

    // C/D layout (m89): col = lane&15, row = (lane>>4)*4 + j
    #pragma unroll
    for (int mi = 0; mi < 2; ++mi) {
        const int row0 = bm + wr * 32 + mi * 16 + ls * 4;
        #pragma unroll
        for (int ni = 0; ni < 2; ++ni) {
            const int col = bn + wc * 32 + ni * 16 + lr;
            const float bv = bias ? bias[col] : 0.0f;
            #pragma unroll
            for (int j = 0; j < 4; ++j) {
                const float v = acc[mi][ni][j] + bv;
                if (OUT_BF16)
                    ((unsigned short*)Cout)[(size_t)(row0 + j) * N + col] = f2bf(v);
                else
                    ((float*)Cout)[(size_t)(row0 + j) * N + col] = v;
            }
        }
    }
}

// ---------------------------------------------------------------------------
// Fused softmax + rolling dynamic conv (proven R9 version).
// Block = (4 consecutive t, one b), 64 threads (1 wave).
// ---------------------------------------------------------------------------
__global__ __launch_bounds__(64) void dynconv_fused(const unsigned short* __restrict__ hb,
                                                    const unsigned short* __restrict__ lgb,
                                                    unsigned short* __restrict__ cvb) {
    __shared__ float w_s[64][33];

    const int bid = blockIdx.x;
    const int u   = (bid & 7) * 256 + (bid >> 3);   // 2048 % 8 == 0, bijective
    const int tg  = u >> 2;
    const int b   = u & 3;
    const int t0  = tg * 4;
    const int tid = threadIdx.x;

    {
        const int dt = tid >> 4, hd = tid & 15;
        const unsigned short* lp = lgb + (size_t)((t0 + dt) * BB + b) * NPAD + hd * KK;
        float e[KK];
        float mx = -1e30f;
        #pragma unroll
        for (int k = 0; k < KK; ++k) { e[k] = bf2f(lp[k]); mx = fmaxf(mx, e[k]); }
        float sm = 0.f;
        #pragma unroll
        for (int k = 0; k < KK; ++k) { e[k] = __expf(e[k] - mx); sm += e[k]; }
        const float inv = 1.f / sm;
        #pragma unroll
        for (int k = 0; k < KK; ++k) w_s[tid][k] = e[k] * inv;
    }
    __syncthreads();

    const int c0 = tid * 8;
    const int hd = tid >> 2;
    float acc[4][8] = {};
    #pragma unroll
    for (int j = 0; j < 34; ++j) {
        const int tt = t0 - PP + j;
        if ((unsigned)tt >= TT) continue;
        const ushort8 hv = *(const ushort8*)&hb[(size_t)((tt * BB + b) * CC) + c0];
        float hf[8];
        #pragma unroll
        for (int cc = 0; cc < 8; ++cc) hf[cc] = bf2f(hv[cc]);
        #pragma unroll
        for (int dt = 0; dt < 4; ++dt) {
            const int k = j - dt;
            if (k < 0 || k >= KK) continue;
            const float wk = w_s[dt * 16 + hd][k];
            #pragma unroll
            for (int cc = 0; cc < 8; ++cc) acc[dt][cc] = fmaf(hf[cc], wk, acc[dt][cc]);
        }
    }
    #pragma unroll
    for (int dt = 0; dt < 4; ++dt) {
        ushort8 o;
        #pragma unroll
        for (int cc = 0; cc < 8; ++cc) o[cc] = f2bf(acc[dt][cc]);
        *(ushort8*)&cvb[(size_t)(((t0 + dt) * BB + b) * CC) + c0] = o;
    }
}

extern "C" void kernel_launch(void* const* d_in, const int* in_sizes, int n_in,
                              void* d_out, int out_size, void* d_ws, size_t ws_size,
                              hipStream_t stream) {
    const float* x  = (const float*)d_in[0];
    const float* W1 = (const float*)d_in[1];
    const float* b1 = (const float*)d_in[2];
    const float* Wl = (const float*)d_in[3];
    const float* W2 = (const float*)d_in[4];
    const float* b2 = (const float*)d_in[5];
    float* out = (float*)d_out;

    // workspace layout (all bf16 except out)
    unsigned short* xb  = (unsigned short*)d_ws;             // 8 MB
    unsigned short* hb  = xb  + (size_t)MM * CC;             // 8 MB
    unsigned short* cvb = hb  + (size_t)MM * CC;             // 8 MB
    unsigned short* W1b = cvb + (size_t)MM * CC;             // 0.5 MB
    unsigned short* Wlb = W1b + (size_t)CC * CC;             // 0.5 MB (padded)
    unsigned short* W2b = Wlb + (size_t)NPAD * CC;           // 0.5 MB
    unsigned short* lgb = W2b + (size_t)CC * CC;             // 8 MB bf16 logits

    // single cast dispatch (x + all weights)
    cast_all<<<4096 + 768, 256, 0, stream>>>(x, W1, Wl, W2, xb, W1b, Wlb, W2b);

    const int nblk = (MM / GBM) * (CC / GBN);   // 64 * 8 = 512

    // 1) h = x @ W1^T + b1   (bf16 out)
    gemm_nt_mfma<true><<<nblk, 512, 0, stream>>>(xb, W1b, b1, hb, CC, CC / GBN);
    // 2) logits = h @ Wl^T   (bf16 out, padded N)
    gemm_nt_mfma<true><<<nblk, 512, 0, stream>>>(hb, Wlb, nullptr, lgb, NPAD, NPAD / GBN);
    // 3+4) fused softmax + rolling dynamic conv (bf16 out)
    dynconv_fused<<<TT * BB / 4, 64, 0, stream>>>(hb, lgb, cvb);
    // 5) out = cv @ W2^T + b2  (fp32 out)
    gemm_nt_mfma<false><<<nblk, 512, 0, stream>>>(cvb, W2b, b2, out, CC, CC / GBN);
}